// Round 12
// baseline (246.669 us; speedup 1.0000x reference)
//
#include <hip/hip_runtime.h>
#include <cstdint>
#include <cstddef>

#define B_    8
#define N_    2048
#define FIN   128
#define FOUT  64
#define ALPHA 0.2f
#define LOG2E 1.4426950408889634f

typedef __attribute__((ext_vector_type(8))) _Float16 half8;
typedef __attribute__((ext_vector_type(4))) _Float16 half4;
typedef __attribute__((ext_vector_type(4))) float float4v;

// ---------------------------------------------------------------------------
// Kernel 1: wh = x @ W via MFMA (split-fp16 compensation, fp32-level
// accuracy), whT fp16, s1 = wh@a1, s2 = wh@a2. Unchanged (proven).
// ---------------------------------------------------------------------------
__global__ __launch_bounds__(256, 2) void k1_wh(
    const float* __restrict__ x, const float* __restrict__ W,
    const float* __restrict__ w2,
    _Float16* __restrict__ whT, float* __restrict__ s1, float* __restrict__ s2)
{
    __shared__ __attribute__((aligned(16))) _Float16 xth[32][136];
    __shared__ __attribute__((aligned(16))) _Float16 xtl[32][136];
    __shared__ float s1p[4][32];
    __shared__ float s2p[4][32];

    int t = threadIdx.x, lane = t & 63, w = t >> 6;
    int b = blockIdx.x >> 6;
    int r0 = (blockIdx.x & 63) << 5;          // 32 rows per block
    const float* xb = x + ((size_t)b * N_ + r0) * FIN;

    #pragma unroll
    for (int j = 0; j < 4; ++j) {
        int idx = t + j * 256;
        int row = idx >> 5;
        int k0 = (idx & 31) * 4;
        float4 v = ((const float4*)xb)[idx];
        float vv[4] = {v.x, v.y, v.z, v.w};
        half4 h, l;
        #pragma unroll
        for (int e = 0; e < 4; ++e) {
            _Float16 hi = (_Float16)vv[e];
            h[e] = hi;
            l[e] = (_Float16)(vv[e] - (float)hi);
        }
        *(half4*)&xth[row][k0] = h;
        *(half4*)&xtl[row][k0] = l;
    }
    __syncthreads();

    int l15 = lane & 15, quad = lane >> 4;
    int f0 = w * 16;

    half8 bh[4], bl[4];
    const float* wcol = W + (f0 + l15);
    #pragma unroll
    for (int c = 0; c < 4; ++c) {
        #pragma unroll
        for (int e = 0; e < 8; ++e) {
            float v = wcol[(size_t)(c * 32 + quad * 8 + e) * FOUT];
            _Float16 hi = (_Float16)v;
            bh[c][e] = hi;
            bl[c][e] = (_Float16)(v - (float)hi);
        }
    }
    float a1f = w2[f0 + l15], a2f = w2[FOUT + f0 + l15];

    #pragma unroll
    for (int rt = 0; rt < 2; ++rt) {
        float4v acc = {0.f, 0.f, 0.f, 0.f};
        #pragma unroll
        for (int c = 0; c < 4; ++c) {
            half8 ah = *(const half8*)&xth[rt * 16 + l15][c * 32 + quad * 8];
            half8 al = *(const half8*)&xtl[rt * 16 + l15][c * 32 + quad * 8];
            acc = __builtin_amdgcn_mfma_f32_16x16x32_f16(ah, bh[c], acc, 0, 0, 0);
            acc = __builtin_amdgcn_mfma_f32_16x16x32_f16(ah, bl[c], acc, 0, 0, 0);
            acc = __builtin_amdgcn_mfma_f32_16x16x32_f16(al, bh[c], acc, 0, 0, 0);
        }
        half4 hv;
        #pragma unroll
        for (int reg = 0; reg < 4; ++reg) hv[reg] = (_Float16)acc[reg];
        *(half4*)(whT + ((size_t)b * FOUT + f0 + l15) * N_ + r0 + rt * 16 + quad * 4) = hv;

        #pragma unroll
        for (int reg = 0; reg < 4; ++reg) {
            float v1 = acc[reg] * a1f;
            float v2 = acc[reg] * a2f;
            #pragma unroll
            for (int m = 1; m <= 8; m <<= 1) {
                v1 += __shfl_xor(v1, m);
                v2 += __shfl_xor(v2, m);
            }
            if (l15 == 0) {
                s1p[w][rt * 16 + quad * 4 + reg] = v1;
                s2p[w][rt * 16 + quad * 4 + reg] = v2;
            }
        }
    }
    __syncthreads();
    if (t < 32) {
        float v = s1p[0][t] + s1p[1][t] + s1p[2][t] + s1p[3][t];
        s1[(size_t)b * N_ + r0 + t] = v;
    } else if (t < 64) {
        int r = t - 32;
        float v = s2p[0][r] + s2p[1][r] + s2p[2][r] + s2p[3][r];
        s2[(size_t)b * N_ + r0 + r] = v;
    }
}

// ---------------------------------------------------------------------------
// Kernel 2: R3's DMA flash-attention, body executed TWICE per dispatch
// (MEASUREMENT ROUND). Pass 0's results are kept alive via asm sinks
// (rule #17: prevents DCE without cost) and discarded; pass 1 is the real
// computation, bit-identical to the passing R3/R11 kernels. The dispatch
// lands ~2x the production k2 (~130 us) -> finally exceeds the 77 us
// harness fills and gets a full rocprof counter row. All rate counters
// (VALUBusy/MfmaUtil/Occupancy/conflicts) are an honest 2x profile.
// ---------------------------------------------------------------------------
__global__ __launch_bounds__(256, 4) void k2_attn(
    const int* __restrict__ adj, const _Float16* __restrict__ whT,
    const float* __restrict__ s1, const float* __restrict__ s2,
    float* __restrict__ out)
{
    __shared__ __attribute__((aligned(16))) int adjS[2][16][256];       // 32 KB
    __shared__ __attribute__((aligned(16))) _Float16 pT[2][16][264];    // 16.5 KB
    __shared__ float lL[16];
    __shared__ float smaxL[4];

    int t = threadIdx.x, lane = t & 63, w = t >> 6;
    int b = blockIdx.x >> 7;
    int i0 = (blockIdx.x & 127) << 4;

    // --- exact S2MAX over batch b (8 KB, L2-hot) ---
    const float4* s2v = (const float4*)(s2 + (size_t)b * N_);
    float4 ua_ = s2v[t], ub_ = s2v[t + 256];
    float vm = fmaxf(fmaxf(fmaxf(ua_.x, ua_.y), fmaxf(ua_.z, ua_.w)),
                     fmaxf(fmaxf(ub_.x, ub_.y), fmaxf(ub_.z, ub_.w)));
    #pragma unroll
    for (int m = 32; m >= 1; m >>= 1) vm = fmaxf(vm, __shfl_xor(vm, m));
    if (lane == 0) smaxL[w] = vm;
    __syncthreads();
    float s2max = fmaxf(fmaxf(smaxL[0], smaxL[1]), fmaxf(smaxL[2], smaxL[3]));

    int l15 = lane & 15, quad = lane >> 4;
    int f0 = w * 16;

    // per-row folded constants (wave w owns rows w*4..w*4+3)
    float c1[4], c2[4];
    #pragma unroll
    for (int rr = 0; rr < 4; ++rr) {
        float sv = s1[(size_t)b * N_ + i0 + w * 4 + rr];   // wave-uniform
        float mm = sv + s2max;
        float mh = fmaxf(mm, ALPHA * mm);    // leaky(s1_i + s2max) >= row max
        c1[rr] = (sv - mh) * LOG2E;
        c2[rr] = (ALPHA * sv - mh) * LOG2E;
    }

    // per-lane global bases
    const int* adjL = adj + ((size_t)b * N_ + i0 + w * 4) * N_ + lane * 4;
    const float* s2L = s2 + (size_t)b * N_ + lane * 4;
    const _Float16* wB = whT + ((size_t)b * FOUT + f0 + l15) * N_ + quad * 8;
    float4 Sb[2];

#define STAGE(cn, bf) do {                                                   \
        _Pragma("unroll")                                                    \
        for (int rr = 0; rr < 4; ++rr) {                                     \
            const int* src_ = adjL + (size_t)rr * N_ + (cn) * 256;           \
            __builtin_amdgcn_global_load_lds(                                \
                (const __attribute__((address_space(1))) void*)src_,         \
                (__attribute__((address_space(3))) void*)&adjS[bf][w * 4 + rr][0], \
                16, 0, 0);                                                   \
        }                                                                    \
        Sb[bf] = *(const float4*)(s2L + (cn) * 256);                         \
    } while (0)

    float4v acc = {0.f, 0.f, 0.f, 0.f};
    float lacc[4];

    #pragma unroll 1
    for (int pass = 0; pass < 2; ++pass) {
        acc = (float4v){0.f, 0.f, 0.f, 0.f};
        #pragma unroll
        for (int rr = 0; rr < 4; ++rr) lacc[rr] = 0.f;

        STAGE(0, 0);                          // prologue: chunk 0 in flight

        #pragma unroll
        for (int c = 0; c < 8; ++c) {
            // bf(c) into regs FIRST (older than the new stage)
            half8 bfr[8];
            const _Float16* wp = wB + c * 256;
            #pragma unroll
            for (int kk = 0; kk < 8; ++kk) bfr[kk] = *(const half8*)(wp + kk * 32);

            if (c < 7) {
                STAGE(c + 1, (c + 1) & 1);
                asm volatile("s_waitcnt vmcnt(13)" ::: "memory"); // drain chunk c DMA
            } else {
                asm volatile("s_waitcnt vmcnt(8)" ::: "memory");  // leave bf(7) in flight
            }
            __builtin_amdgcn_sched_barrier(0);

            // p-compute chunk c from adjS[c&1] + Sb[c&1]
            {
                float4 sv = Sb[c & 1];
                float u[4]  = {sv.x * LOG2E, sv.y * LOG2E, sv.z * LOG2E, sv.w * LOG2E};
                float ua[4] = {u[0] * ALPHA, u[1] * ALPHA, u[2] * ALPHA, u[3] * ALPHA};
                #pragma unroll
                for (int rr = 0; rr < 4; ++rr) {
                    int r = w * 4 + rr;
                    int4 av = *(const int4*)&adjS[c & 1][r][lane * 4];
                    int aa[4] = {av.x, av.y, av.z, av.w};
                    half4 pf;
                    float ls = 0.f;
                    #pragma unroll
                    for (int e = 0; e < 4; ++e) {
                        float tt = fmaxf(c1[rr] + u[e], c2[rr] + ua[e]);
#if __has_builtin(__builtin_amdgcn_exp2f)
                        float p = __builtin_amdgcn_exp2f(tt);
#else
                        float p = exp2f(tt);
#endif
                        p = (aa[e] > 0) ? p : 0.f;
                        ls += p;
                        pf[e] = (_Float16)p;
                    }
                    lacc[rr] += ls;
                    *(half4*)&pT[c & 1][r][lane * 4] = pf;
                }
            }

            if (pass == 1 && c == 7) {
                // publish row sums before the last barrier (real pass only)
                #pragma unroll
                for (int rr = 0; rr < 4; ++rr) {
                    float v = lacc[rr];
                    #pragma unroll
                    for (int m = 32; m >= 1; m >>= 1) v += __shfl_xor(v, m);
                    if (lane == 0) lL[w * 4 + rr] = v;
                }
            }

            __syncthreads();   // publish pT[c&1]

            // MFMA on pT[c&1] with reg-resident B
            #pragma unroll
            for (int kk = 0; kk < 8; ++kk) {
                half8 af = *(const half8*)&pT[c & 1][l15][kk * 32 + quad * 8];
                acc = __builtin_amdgcn_mfma_f32_16x16x32_f16(af, bfr[kk], acc, 0, 0, 0);
            }
        }

        if (pass == 0) {
            // keep pass-0 results alive (rule #17), then discard
            asm volatile("" :: "v"(acc[0]), "v"(acc[1]), "v"(acc[2]), "v"(acc[3]));
            asm volatile("" :: "v"(lacc[0]), "v"(lacc[1]), "v"(lacc[2]), "v"(lacc[3]));
        }
    }
#undef STAGE

    // epilogue: normalize, ELU, store. D: row=quad*4+reg, col=f0+l15
    #pragma unroll
    for (int reg = 0; reg < 4; ++reg) {
        int row = quad * 4 + reg;
        float val = acc[reg] / lL[row];
        val = (val > 0.f) ? val : (__expf(val) - 1.f);   // ELU
        out[((size_t)b * N_ + i0 + row) * FOUT + f0 + l15] = val;
    }
}

// ---------------------------------------------------------------------------
extern "C" void kernel_launch(void* const* d_in, const int* in_sizes, int n_in,
                              void* d_out, int out_size, void* d_ws, size_t ws_size,
                              hipStream_t stream) {
    const float* x   = (const float*)d_in[0];
    const int*   adj = (const int*)d_in[1];
    const float* W   = (const float*)d_in[2];
    const float* w2  = (const float*)d_in[3];
    float* out = (float*)d_out;

    char* ws = (char*)d_ws;
    _Float16* whT = (_Float16*)ws;                              // 2 MiB
    float* s1  = (float*)(ws + 2097152);                        // 64 KiB
    float* s2  = (float*)(ws + 2097152 + 65536);                // 64 KiB

    k1_wh<<<(B_ * N_) / 32, 256, 0, stream>>>(x, W, w2, whT, s1, s2);
    k2_attn<<<(B_ * N_) / 16, 256, 0, stream>>>(adj, whT, s1, s2, out);
}